// Round 23
// baseline (74.638 us; speedup 1.0000x reference)
//
#include <hip/hip_runtime.h>
#include <hip/hip_bf16.h>
#include <math.h>

#define B_N    32768
#define XD     60
#define YD     10
#define NK     64
#define HID    2048
#define OUTD   704   // NK + NK*YD
#define TS     64    // rows per tile
#define MAXT   576   // >= 512 full tiles + 64 partials; divisible by 8 (XCD swizzle)

#define LBLK   128   // label blocks (B/256)

typedef float f32x4_t __attribute__((ext_vector_type(4)));

#define MFMA8(a, b, c) __builtin_amdgcn_mfma_f32_16x16x32_fp8_fp8(a, b, c, 0, 0, 0)

__device__ __forceinline__ unsigned short bf16bits(float f) {
    __hip_bfloat16 h = __float2bfloat16(f);
    return *reinterpret_cast<unsigned short*>(&h);
}
__device__ __forceinline__ float bff(unsigned short b) {
    unsigned int u = ((unsigned int)b) << 16;
    return __uint_as_float(u);
}
// pack 4 floats -> 4 e4m3 bytes (RNE, saturating) via HW cvt
__device__ __forceinline__ int pk4(float a, float b, float c, float d) {
    int p = __builtin_amdgcn_cvt_pk_fp8_f32(a, b, 0, false);
    return __builtin_amdgcn_cvt_pk_fp8_f32(c, d, p, true);
}

// ---------------- kA: labels+counts (blocks 0..127) || fp8 weight packs (128..319)
__global__ __launch_bounds__(256) void k_a(const float* __restrict__ y,
                                           const float* __restrict__ centers,
                                           const float* __restrict__ W1,
                                           const float* __restrict__ b1,
                                           const float* __restrict__ W2,
                                           int* __restrict__ labels,
                                           int* __restrict__ counts,
                                           unsigned char* __restrict__ W1F,
                                           unsigned char* __restrict__ W2F,
                                           unsigned char* __restrict__ W2GF) {
    __shared__ __align__(16) char smem[40960];
    int bid = blockIdx.x, t = threadIdx.x;
    int l  = t & 63;
    int lr = l & 15;
    int lg = l >> 4;

    if (bid < LBLK) {
        float* cs = (float*)smem; float* sc = cs + 640; int* lh = (int*)(cs + 704);
        for (int i = t; i < NK * YD; i += 256) cs[i] = centers[i];
        if (t < NK) lh[t] = 0;
        __syncthreads();
        if (t < NK) { float s = 0.f; for (int j = 0; j < YD; ++j) { float v = cs[t*YD+j]; s += v*v; } sc[t] = s; }
        __syncthreads();
        int i = bid * 256 + t;
        float ly[YD]; float sy = 0.f;
        for (int j = 0; j < YD; ++j) { ly[j] = y[i*YD+j]; sy += ly[j]*ly[j]; }
        float best = 1e30f; int lab = 0;
        for (int k = 0; k < NK; ++k) {
            float dot = 0.f;
            #pragma unroll
            for (int j = 0; j < YD; ++j) dot += ly[j] * cs[k*YD+j];
            float d = sy - 2.f*dot + sc[k];
            if (d < best) { best = d; lab = k; }
        }
        labels[i] = lab;
        atomicAdd(&lh[lab], 1);
        __syncthreads();
        if (t < NK && lh[t] > 0) atomicAdd(&counts[t], lh[t]);
    } else if (bid < LBLK + 64) {
        int b = bid - LBLK, s = b >> 2, w = b & 3;
        unsigned short (*lds)[32] = (unsigned short(*)[32])smem;
        int n0 = 128*s + 32*w;
        for (int idx = t; idx < 64*32; idx += 256) {
            int kk = idx >> 5, c = idx & 31;
            float v = (kk < XD) ? 16.f * W1[(size_t)(YD + kk) * HID + n0 + c]
                                : ((kk == XD) ? 16.f * b1[n0 + c] : 0.f);
            lds[kk][c] = bf16bits(v);
        }
        __syncthreads();
        if (t < 128) {
            int n2 = (t >> 6) & 1;
            float v[16];
            #pragma unroll
            for (int ks = 0; ks < 2; ++ks)
                #pragma unroll
                for (int bb = 0; bb < 8; ++bb)
                    v[8*ks + bb] = bff(lds[32*ks + 8*lg + bb][16*n2 + lr]);
            uint4 o;
            o.x = pk4(v[0],v[1],v[2],v[3]);   o.y = pk4(v[4],v[5],v[6],v[7]);
            o.z = pk4(v[8],v[9],v[10],v[11]); o.w = pk4(v[12],v[13],v[14],v[15]);
            *reinterpret_cast<uint4*>(&W1F[((s*4 + w)*2 + n2)*1024 + l*16]) = o;
        }
    } else if (bid < LBLK + 128) {
        int b = bid - LBLK - 64, s = b >> 2, w = b & 3;
        unsigned short (*lds)[64] = (unsigned short(*)[64])smem;
        int k0 = 128*s + 32*w;
        for (int idx = t; idx < 32*64; idx += 256) {
            int kk = idx >> 6, c = idx & 63;
            lds[kk][c] = bf16bits(16.f * W2[(size_t)(k0 + kk) * OUTD + c]);
        }
        __syncthreads();
        int q = t >> 6;
        float v[8];
        #pragma unroll
        for (int bb = 0; bb < 8; ++bb) v[bb] = bff(lds[8*lg + bb][16*q + lr]);
        uint2 o;
        o.x = pk4(v[0],v[1],v[2],v[3]); o.y = pk4(v[4],v[5],v[6],v[7]);
        *reinterpret_cast<uint2*>(&W2F[((s*4 + w)*2 + (q >> 1))*1024 + l*16 + (q & 1)*8]) = o;
    } else {
        int b = bid - LBLK - 128, s = b >> 2, w = b & 3;
        unsigned short (*lds)[640] = (unsigned short(*)[640])smem;
        int k0 = 128*s + 32*w;
        for (int idx = t; idx < 32*640; idx += 256) {
            int kk = idx / 640, c = idx - kk*640;
            lds[kk][c] = bf16bits(16.f * W2[(size_t)(k0 + kk) * OUTD + NK + c]);
        }
        __syncthreads();
        for (int g = t >> 6; g < 64; g += 4) {
            float v[8];
            #pragma unroll
            for (int bb = 0; bb < 8; ++bb)
                v[bb] = (lr < YD) ? bff(lds[8*lg + bb][10*g + lr]) : 0.f;
            uint2 o;
            o.x = pk4(v[0],v[1],v[2],v[3]); o.y = pk4(v[4],v[5],v[6],v[7]);
            *reinterpret_cast<uint2*>(&W2GF[(((g*16 + s)*4 + w) << 9) + l*8]) = o;
        }
    }
}

// ---------------- kB: scatter (needs completed labels+counts) ----------------
__global__ __launch_bounds__(256) void k_b(const int* __restrict__ labels,
                                           const int* __restrict__ counts,
                                           int* __restrict__ cursor,      // zero-based
                                           int* __restrict__ perm) {
    __shared__ int lh[NK], lbase[NK];
    int t = threadIdx.x, bid = blockIdx.x;
    if (t < NK) lh[t] = 0;
    __syncthreads();
    int i = bid * 256 + t;
    int lab = labels[i];
    int rank = atomicAdd(&lh[lab], 1);
    __syncthreads();
    if (t < NK) {
        int c = counts[t];
        int s = c;
        #pragma unroll
        for (int d = 1; d < 64; d <<= 1) {
            int v = __shfl_up(s, d);
            if (t >= d) s += v;
        }
        int offs = s - c;
        if (lh[t] > 0) lbase[t] = offs + atomicAdd(&cursor[t], lh[t]);
    }
    __syncthreads();
    perm[lbase[lab] + rank] = i;
}

// per-slab weight registers: 5 asm-forced loads, 18 VGPRs per set
struct WR { uint4 w0, w1, q0, q1; uint2 qg; };

__device__ __forceinline__ void loadw_asm(WR& r, int s_,
                                          const unsigned char* __restrict__ W1F,
                                          const unsigned char* __restrict__ W2F,
                                          const unsigned char* __restrict__ W2GF,
                                          int g, int w, int l) {
    const unsigned char* a0 = W1F + (s_*4 + w)*2048 + l*16;
    const unsigned char* a1 = a0 + 1024;
    const unsigned char* b0 = W2F + (s_*4 + w)*2048 + l*16;
    const unsigned char* b1 = b0 + 1024;
    const unsigned char* c0 = W2GF + (((g*16 + s_)*4 + w) << 9) + l*8;
    asm volatile("global_load_dwordx4 %0, %1, off" : "=&v"(r.w0) : "v"(a0));
    asm volatile("global_load_dwordx4 %0, %1, off" : "=&v"(r.w1) : "v"(a1));
    asm volatile("global_load_dwordx4 %0, %1, off" : "=&v"(r.q0) : "v"(b0));
    asm volatile("global_load_dwordx4 %0, %1, off" : "=&v"(r.q1) : "v"(b1));
    asm volatile("global_load_dwordx2 %0, %1, off" : "=&v"(r.qg) : "v"(c0));
}
#define WAIT5() do { asm volatile("s_waitcnt vmcnt(5)" ::: "memory"); \
                     __builtin_amdgcn_sched_barrier(0); } while (0)
#define DRAIN() do { asm volatile("s_waitcnt vmcnt(0)" ::: "memory"); \
                     __builtin_amdgcn_sched_barrier(0); } while (0)

union U4 { uint4 q; long long l2[2]; };
union U2 { uint2 u; long long ll; };

// slab body, 3-PHASE BATCHED: (1) all GEMM1 + packs, (2) all 16 bpermutes
// issued back-to-back (one amortized DS wait instead of 4), (3) all GEMM2.
// Same math as R22's per-mt form; exposes 4x phase-internal ILP so the DS
// latency is paid once per slab.
__device__ __forceinline__ void slab_body(const WR& r,
                                          const U2 (&xf)[4][2], f32x4_t (&acc2)[4][5],
                                          int idx0, int idx1, bool lo) {
    U4 w0, w1, q0, q1; w0.q = r.w0; w1.q = r.w1; q0.q = r.q0; q1.q = r.q1;
    U2 qg; qg.u = r.qg;
    int h0w0, h0w1, h0w2, h0w3, h1w0, h1w1, h1w2, h1w3;
    // ---- phase 1: all GEMM1 (16 MFMA, 8 independent chains) + 8 packs
    {
        f32x4_t h0a = {0,0,0,0}, h1a = {0,0,0,0}, h0b = {0,0,0,0}, h1b = {0,0,0,0};
        f32x4_t h0c = {0,0,0,0}, h1c = {0,0,0,0}, h0d = {0,0,0,0}, h1d = {0,0,0,0};
        h0a = MFMA8(w0.l2[0], xf[0][0].ll, h0a); h0a = MFMA8(w0.l2[1], xf[0][1].ll, h0a);
        h1a = MFMA8(w1.l2[0], xf[0][0].ll, h1a); h1a = MFMA8(w1.l2[1], xf[0][1].ll, h1a);
        h0b = MFMA8(w0.l2[0], xf[1][0].ll, h0b); h0b = MFMA8(w0.l2[1], xf[1][1].ll, h0b);
        h1b = MFMA8(w1.l2[0], xf[1][0].ll, h1b); h1b = MFMA8(w1.l2[1], xf[1][1].ll, h1b);
        h0c = MFMA8(w0.l2[0], xf[2][0].ll, h0c); h0c = MFMA8(w0.l2[1], xf[2][1].ll, h0c);
        h1c = MFMA8(w1.l2[0], xf[2][0].ll, h1c); h1c = MFMA8(w1.l2[1], xf[2][1].ll, h1c);
        h0d = MFMA8(w0.l2[0], xf[3][0].ll, h0d); h0d = MFMA8(w0.l2[1], xf[3][1].ll, h0d);
        h1d = MFMA8(w1.l2[0], xf[3][0].ll, h1d); h1d = MFMA8(w1.l2[1], xf[3][1].ll, h1d);
        h0w0 = pk4(fmaxf(h0a[0],0.f), fmaxf(h0a[1],0.f), fmaxf(h0a[2],0.f), fmaxf(h0a[3],0.f));
        h1w0 = pk4(fmaxf(h1a[0],0.f), fmaxf(h1a[1],0.f), fmaxf(h1a[2],0.f), fmaxf(h1a[3],0.f));
        h0w1 = pk4(fmaxf(h0b[0],0.f), fmaxf(h0b[1],0.f), fmaxf(h0b[2],0.f), fmaxf(h0b[3],0.f));
        h1w1 = pk4(fmaxf(h1b[0],0.f), fmaxf(h1b[1],0.f), fmaxf(h1b[2],0.f), fmaxf(h1b[3],0.f));
        h0w2 = pk4(fmaxf(h0c[0],0.f), fmaxf(h0c[1],0.f), fmaxf(h0c[2],0.f), fmaxf(h0c[3],0.f));
        h1w2 = pk4(fmaxf(h1c[0],0.f), fmaxf(h1c[1],0.f), fmaxf(h1c[2],0.f), fmaxf(h1c[3],0.f));
        h0w3 = pk4(fmaxf(h0d[0],0.f), fmaxf(h0d[1],0.f), fmaxf(h0d[2],0.f), fmaxf(h0d[3],0.f));
        h1w3 = pk4(fmaxf(h1d[0],0.f), fmaxf(h1d[1],0.f), fmaxf(h1d[2],0.f), fmaxf(h1d[3],0.f));
    }
    // ---- phase 2: all 16 bpermutes (independent; latency amortized)
    int pA0 = __builtin_amdgcn_ds_bpermute(idx0, h0w0);
    int pA1 = __builtin_amdgcn_ds_bpermute(idx1, h0w0);
    int pA2 = __builtin_amdgcn_ds_bpermute(idx0, h1w0);
    int pA3 = __builtin_amdgcn_ds_bpermute(idx1, h1w0);
    int pB0 = __builtin_amdgcn_ds_bpermute(idx0, h0w1);
    int pB1 = __builtin_amdgcn_ds_bpermute(idx1, h0w1);
    int pB2 = __builtin_amdgcn_ds_bpermute(idx0, h1w1);
    int pB3 = __builtin_amdgcn_ds_bpermute(idx1, h1w1);
    int pC0 = __builtin_amdgcn_ds_bpermute(idx0, h0w2);
    int pC1 = __builtin_amdgcn_ds_bpermute(idx1, h0w2);
    int pC2 = __builtin_amdgcn_ds_bpermute(idx0, h1w2);
    int pC3 = __builtin_amdgcn_ds_bpermute(idx1, h1w2);
    int pD0 = __builtin_amdgcn_ds_bpermute(idx0, h0w3);
    int pD1 = __builtin_amdgcn_ds_bpermute(idx1, h0w3);
    int pD2 = __builtin_amdgcn_ds_bpermute(idx0, h1w3);
    int pD3 = __builtin_amdgcn_ds_bpermute(idx1, h1w3);
    // ---- phase 3: all GEMM2 (20 MFMA, 20 independent accumulator chains)
    U2 aA, aB, aC, aD;
    aA.u.x = lo ? (unsigned int)pA0 : (unsigned int)pA2;
    aA.u.y = lo ? (unsigned int)pA1 : (unsigned int)pA3;
    aB.u.x = lo ? (unsigned int)pB0 : (unsigned int)pB2;
    aB.u.y = lo ? (unsigned int)pB1 : (unsigned int)pB3;
    aC.u.x = lo ? (unsigned int)pC0 : (unsigned int)pC2;
    aC.u.y = lo ? (unsigned int)pC1 : (unsigned int)pC3;
    aD.u.x = lo ? (unsigned int)pD0 : (unsigned int)pD2;
    aD.u.y = lo ? (unsigned int)pD1 : (unsigned int)pD3;
    acc2[0][0] = MFMA8(q0.l2[0], aA.ll, acc2[0][0]);
    acc2[0][1] = MFMA8(q0.l2[1], aA.ll, acc2[0][1]);
    acc2[0][2] = MFMA8(q1.l2[0], aA.ll, acc2[0][2]);
    acc2[0][3] = MFMA8(q1.l2[1], aA.ll, acc2[0][3]);
    acc2[0][4] = MFMA8(qg.ll,    aA.ll, acc2[0][4]);
    acc2[1][0] = MFMA8(q0.l2[0], aB.ll, acc2[1][0]);
    acc2[1][1] = MFMA8(q0.l2[1], aB.ll, acc2[1][1]);
    acc2[1][2] = MFMA8(q1.l2[0], aB.ll, acc2[1][2]);
    acc2[1][3] = MFMA8(q1.l2[1], aB.ll, acc2[1][3]);
    acc2[1][4] = MFMA8(qg.ll,    aB.ll, acc2[1][4]);
    acc2[2][0] = MFMA8(q0.l2[0], aC.ll, acc2[2][0]);
    acc2[2][1] = MFMA8(q0.l2[1], aC.ll, acc2[2][1]);
    acc2[2][2] = MFMA8(q1.l2[0], aC.ll, acc2[2][2]);
    acc2[2][3] = MFMA8(q1.l2[1], aC.ll, acc2[2][3]);
    acc2[2][4] = MFMA8(qg.ll,    aC.ll, acc2[2][4]);
    acc2[3][0] = MFMA8(q0.l2[0], aD.ll, acc2[3][0]);
    acc2[3][1] = MFMA8(q0.l2[1], aD.ll, acc2[3][1]);
    acc2[3][2] = MFMA8(q1.l2[0], aD.ll, acc2[3][2]);
    acc2[3][3] = MFMA8(q1.l2[1], aD.ll, acc2[3][3]);
    acc2[3][4] = MFMA8(qg.ll,    aD.ll, acc2[3][4]);
}

// ---------------- fused + in-kernel finalize (ticket; no threadfence) ------
__global__ __launch_bounds__(256, 2) void k_fused(const float* __restrict__ x,
                                                  const unsigned char* __restrict__ W1F,
                                                  const unsigned char* __restrict__ W2F,
                                                  const unsigned char* __restrict__ W2GF,
                                                  const float* __restrict__ b2,
                                                  const float* __restrict__ y,
                                                  const float* __restrict__ centers,
                                                  const int* __restrict__ counts,
                                                  const int* __restrict__ perm,
                                                  float* __restrict__ accum,
                                                  int* __restrict__ ticket,
                                                  float* __restrict__ out) {
    __shared__ __align__(16) union {
        unsigned char xb[TS][80];   // fp8 x tile (gather phase)
        float o[TS][84];            // epilogue overlay
    } u;
    __shared__ int   rows_s[TS];
    __shared__ int   dsc[3];   // g, off, nrows

    int phys = blockIdx.x, t = threadIdx.x;
    int bid  = (phys & 7) * (MAXT / 8) + (phys >> 3);   // XCD chunk swizzle (bijective)
    int l  = t & 63;
    int w  = t >> 6;
    int lr = l & 15;
    int lg = l >> 4;

    // in-block tile descriptor: wave 0 scans counts
    if (t == 0) dsc[2] = 0;
    if (t < 64) {
        int c = counts[t];
        int ntm = (c + TS - 1) / TS;
        int sc = c, st = ntm;
        #pragma unroll
        for (int d = 1; d < 64; d <<= 1) {
            int vc = __shfl_up(sc, d);
            int vt = __shfl_up(st, d);
            if (t >= d) { sc += vc; st += vt; }
        }
        int offc  = sc - c;
        int tbase = st - ntm;
        if (bid >= tbase && bid < tbase + ntm) {
            int k = bid - tbase;
            dsc[0] = t;
            dsc[1] = offc + TS * k;
            dsc[2] = min(TS, c - TS * k);
        }
    }
    __syncthreads();
    int g = dsc[0], off = dsc[1], nrows = dsc[2];

    if (nrows == 0) {
        if (t == 0) {
            int old = atomicAdd(ticket, 1);
            if (old == MAXT - 1) {
                float ce = atomicAdd(&accum[0], 0.f);
                float ms = atomicAdd(&accum[1], 0.f);
                out[0] = ce / (float)B_N + 100.f * ms / ((float)B_N * (float)YD);
            }
        }
        return;
    }

    if (t < TS) rows_s[t] = (t < nrows) ? perm[off + t] : -1;
    __syncthreads();

    // gather x rows -> LDS fp8; col 60 = 1.0 (bias lane, e4m3 0x38), 61..79 = 0
    {
        int c4 = t & 15;
        #pragma unroll
        for (int it = 0; it < 4; ++it) {
            int r = 16 * it + (t >> 4);
            int row = rows_s[r];
            if (c4 < 15) {
                int pk = 0;
                if (row >= 0) {
                    float4 v = *reinterpret_cast<const float4*>(&x[(size_t)row * XD + 4 * c4]);
                    pk = pk4(v.x, v.y, v.z, v.w);
                }
                *reinterpret_cast<unsigned int*>(&u.xb[r][4 * c4]) = (unsigned int)pk;
            } else {
                *reinterpret_cast<unsigned int*>(&u.xb[r][60]) = (row >= 0) ? 0x00000038u : 0u;
                uint4 z = {0, 0, 0, 0};
                *reinterpret_cast<uint4*>(&u.xb[r][64]) = z;
            }
        }
    }
    __syncthreads();

    U2 xf[4][2];
    #pragma unroll
    for (int mt = 0; mt < 4; ++mt)
        #pragma unroll
        for (int ks = 0; ks < 2; ++ks)
            xf[mt][ks].u = *reinterpret_cast<const uint2*>(&u.xb[16*mt + lr][32*ks + 8*lg]);

    f32x4_t acc2[4][5];
    #pragma unroll
    for (int mt = 0; mt < 4; ++mt)
        #pragma unroll
        for (int nt = 0; nt < 5; ++nt) acc2[mt][nt] = (f32x4_t){0.f, 0.f, 0.f, 0.f};

    // bpermute indices (byte addressing: 4 * src_lane)
    int idx0 = 4 * (16 * ((2 * lg) & 3) + lr);
    int idx1 = idx0 + 64;
    bool lo  = (lg < 2);

    // depth-2 pipeline: asm loads + counted vmcnt
    WR rA, rB;
    loadw_asm(rA, 0, W1F, W2F, W2GF, g, w, l);
    #pragma unroll 1
    for (int s = 0; s < HID / 128; s += 2) {
        loadw_asm(rB, s + 1, W1F, W2F, W2GF, g, w, l);
        WAIT5();
        slab_body(rA, xf, acc2, idx0, idx1, lo);
        loadw_asm(rA, (s + 2 < 16) ? s + 2 : 0, W1F, W2F, W2GF, g, w, l);
        WAIT5();
        slab_body(rB, xf, acc2, idx0, idx1, lo);
    }
    DRAIN();           // dead in-flight tail loads complete before reg reuse
    __syncthreads();   // all xb reads done before overlaying u.o

    // epilogue: sum 4 K-partials (x 1/256 weight prescale), bias in phase 0
    const float inv = 1.f / 256.f;
    for (int wv = 0; wv < 4; ++wv) {
        if (w == wv) {
            #pragma unroll
            for (int mt = 0; mt < 4; ++mt)
                #pragma unroll
                for (int nt = 0; nt < 5; ++nt) {
                    float4 v;
                    v.x = acc2[mt][nt][0] * inv; v.y = acc2[mt][nt][1] * inv;
                    v.z = acc2[mt][nt][2] * inv; v.w = acc2[mt][nt][3] * inv;
                    float4* pp = reinterpret_cast<float4*>(&u.o[16*mt + lr][16*nt + 4*lg]);
                    if (wv == 0) {
                        float bx, by, bz, bw;
                        if (nt < 4) {
                            int c = 16*nt + 4*lg;
                            bx = b2[c]; by = b2[c+1]; bz = b2[c+2]; bw = b2[c+3];
                        } else {
                            int c = 4*lg;
                            bx = (c   < YD) ? b2[NK + g*YD + c  ] : 0.f;
                            by = (c+1 < YD) ? b2[NK + g*YD + c+1] : 0.f;
                            bz = (c+2 < YD) ? b2[NK + g*YD + c+2] : 0.f;
                            bw = (c+3 < YD) ? b2[NK + g*YD + c+3] : 0.f;
                        }
                        v.x += bx; v.y += by; v.z += bz; v.w += bw;
                        *pp = v;
                    } else {
                        float4 cur = *pp;
                        cur.x += v.x; cur.y += v.y; cur.z += v.z; cur.w += v.w;
                        *pp = cur;
                    }
                }
        }
        __syncthreads();
    }

    // per-row loss; rows 0..63 == wave 0 -> shuffle-reduce, one atomic pair
    if (t < TS) {
        float ce_v = 0.f, mse_v = 0.f;
        if (t < nrows) {
            float m = -1e30f;
            for (int c = 0; c < NK; ++c) m = fmaxf(m, u.o[t][c]);
            float s2 = 0.f;
            for (int c = 0; c < NK; ++c) s2 += expf(u.o[t][c] - m);
            float lse = m + logf(s2);
            ce_v = lse - u.o[t][g];
            int row = rows_s[t];
            #pragma unroll
            for (int j = 0; j < YD; ++j) {
                float tr = y[row * YD + j] - centers[g * YD + j];
                float d  = tr - u.o[t][NK + j];
                mse_v += d * d;
            }
        }
        #pragma unroll
        for (int d = 32; d > 0; d >>= 1) {
            ce_v  += __shfl_down(ce_v, d);
            mse_v += __shfl_down(mse_v, d);
        }
        if (t == 0) {
            atomicAdd(&accum[0], ce_v);
            atomicAdd(&accum[1], mse_v);
            asm volatile("s_waitcnt vmcnt(0)" ::: "memory");
            int old = atomicAdd(ticket, 1);
            if (old == MAXT - 1) {
                float ce = atomicAdd(&accum[0], 0.f);
                float ms = atomicAdd(&accum[1], 0.f);
                out[0] = ce / (float)B_N + 100.f * ms / ((float)B_N * (float)YD);
            }
        }
    }
}

extern "C" void kernel_launch(void* const* d_in, const int* in_sizes, int n_in,
                              void* d_out, int out_size, void* d_ws, size_t ws_size,
                              hipStream_t stream) {
    const float* x       = (const float*)d_in[0];
    const float* y       = (const float*)d_in[1];
    const float* centers = (const float*)d_in[2];
    const float* W1      = (const float*)d_in[3];
    const float* b1      = (const float*)d_in[4];
    const float* W2      = (const float*)d_in[5];
    const float* b2      = (const float*)d_in[6];

    char* ws = (char*)d_ws;
    float* accum  = (float*)ws;                        // 2 f32 @ 0
    int* ticket   = (int*)(ws + 128);
    int* counts   = (int*)(ws + 256);                  // 64 ints
    int* cursor   = (int*)(ws + 768);                  // 64 ints (zero-based)
    char* ws2     = ws + 4096;
    int* labels   = (int*)ws2;                                   // 128 KB
    int* perm     = (int*)(ws2 + 131072);                        // 128 KB
    unsigned char* W1F  = (unsigned char*)(ws2 + 262144);        // 128 KB
    unsigned char* W2F  = (unsigned char*)(ws2 + 393216);        // 128 KB
    unsigned char* W2GF = (unsigned char*)(ws2 + 524288);        // 2 MB

    hipMemsetAsync(ws, 0, 1024, stream);   // zero accum + ticket + counts + cursor
    k_a     <<<LBLK + 192, 256, 0, stream>>>(y, centers, W1, b1, W2,
                                             labels, counts, W1F, W2F, W2GF);
    k_b     <<<B_N / 256, 256, 0, stream>>>(labels, counts, cursor, perm);
    k_fused <<<MAXT, 256, 0, stream>>>(x, W1F, W2F, W2GF, b2, y, centers,
                                       counts, perm, accum, ticket, (float*)d_out);
}

// Round 24
// 63.348 us; speedup vs baseline: 1.1782x; 1.1782x over previous
//
#include <hip/hip_runtime.h>
#include <hip/hip_bf16.h>
#include <math.h>

#define B_N    32768
#define XD     60
#define YD     10
#define NK     64
#define HID    2048
#define OUTD   704   // NK + NK*YD
#define TS     64    // rows per tile
#define MAXT   576   // >= 512 full tiles + 64 partials; divisible by 8 (XCD swizzle)

#define LBLK   128   // label blocks (B/256)

typedef float f32x4_t __attribute__((ext_vector_type(4)));

#define MFMA8(a, b, c) __builtin_amdgcn_mfma_f32_16x16x32_fp8_fp8(a, b, c, 0, 0, 0)

__device__ __forceinline__ unsigned short bf16bits(float f) {
    __hip_bfloat16 h = __float2bfloat16(f);
    return *reinterpret_cast<unsigned short*>(&h);
}
__device__ __forceinline__ float bff(unsigned short b) {
    unsigned int u = ((unsigned int)b) << 16;
    return __uint_as_float(u);
}
// pack 4 floats -> 4 e4m3 bytes (RNE, saturating) via HW cvt
__device__ __forceinline__ int pk4(float a, float b, float c, float d) {
    int p = __builtin_amdgcn_cvt_pk_fp8_f32(a, b, 0, false);
    return __builtin_amdgcn_cvt_pk_fp8_f32(c, d, p, true);
}

// ---------------- kA: labels (0..127) || W1F (128..191) || W2F (192..255)
// || W2GF (256..511; 256 blocks, 16 g-records each for occupancy)
__global__ __launch_bounds__(256) void k_a(const float* __restrict__ y,
                                           const float* __restrict__ centers,
                                           const float* __restrict__ W1,
                                           const float* __restrict__ b1,
                                           const float* __restrict__ W2,
                                           int* __restrict__ labels,
                                           int* __restrict__ counts,
                                           unsigned char* __restrict__ W1F,
                                           unsigned char* __restrict__ W2F,
                                           unsigned char* __restrict__ W2GF) {
    __shared__ __align__(16) char smem[40960];
    int bid = blockIdx.x, t = threadIdx.x;
    int l  = t & 63;
    int lr = l & 15;
    int lg = l >> 4;

    if (bid < LBLK) {
        float* cs = (float*)smem; float* sc = cs + 640; int* lh = (int*)(cs + 704);
        for (int i = t; i < NK * YD; i += 256) cs[i] = centers[i];
        if (t < NK) lh[t] = 0;
        __syncthreads();
        if (t < NK) { float s = 0.f; for (int j = 0; j < YD; ++j) { float v = cs[t*YD+j]; s += v*v; } sc[t] = s; }
        __syncthreads();
        int i = bid * 256 + t;
        float ly[YD]; float sy = 0.f;
        for (int j = 0; j < YD; ++j) { ly[j] = y[i*YD+j]; sy += ly[j]*ly[j]; }
        float best = 1e30f; int lab = 0;
        for (int k = 0; k < NK; ++k) {
            float dot = 0.f;
            #pragma unroll
            for (int j = 0; j < YD; ++j) dot += ly[j] * cs[k*YD+j];
            float d = sy - 2.f*dot + sc[k];
            if (d < best) { best = d; lab = k; }
        }
        labels[i] = lab;
        atomicAdd(&lh[lab], 1);
        __syncthreads();
        if (t < NK && lh[t] > 0) atomicAdd(&counts[t], lh[t]);
    } else if (bid < LBLK + 64) {
        // ---- W1F (scaled x16, b1 folded at k=60)
        int b = bid - LBLK, s = b >> 2, w = b & 3;
        unsigned short (*lds)[32] = (unsigned short(*)[32])smem;
        int n0 = 128*s + 32*w;
        for (int idx = t; idx < 64*32; idx += 256) {
            int kk = idx >> 5, c = idx & 31;
            float v = (kk < XD) ? 16.f * W1[(size_t)(YD + kk) * HID + n0 + c]
                                : ((kk == XD) ? 16.f * b1[n0 + c] : 0.f);
            lds[kk][c] = bf16bits(v);
        }
        __syncthreads();
        if (t < 128) {
            int n2 = (t >> 6) & 1;
            float v[16];
            #pragma unroll
            for (int ks = 0; ks < 2; ++ks)
                #pragma unroll
                for (int bb = 0; bb < 8; ++bb)
                    v[8*ks + bb] = bff(lds[32*ks + 8*lg + bb][16*n2 + lr]);
            uint4 o;
            o.x = pk4(v[0],v[1],v[2],v[3]);   o.y = pk4(v[4],v[5],v[6],v[7]);
            o.z = pk4(v[8],v[9],v[10],v[11]); o.w = pk4(v[12],v[13],v[14],v[15]);
            *reinterpret_cast<uint4*>(&W1F[((s*4 + w)*2 + n2)*1024 + l*16]) = o;
        }
    } else if (bid < LBLK + 128) {
        // ---- W2F (logit cols, scaled x16)
        int b = bid - LBLK - 64, s = b >> 2, w = b & 3;
        unsigned short (*lds)[64] = (unsigned short(*)[64])smem;
        int k0 = 128*s + 32*w;
        for (int idx = t; idx < 32*64; idx += 256) {
            int kk = idx >> 6, c = idx & 63;
            lds[kk][c] = bf16bits(16.f * W2[(size_t)(k0 + kk) * OUTD + c]);
        }
        __syncthreads();
        int q = t >> 6;
        float v[8];
        #pragma unroll
        for (int bb = 0; bb < 8; ++bb) v[bb] = bff(lds[8*lg + bb][16*q + lr]);
        uint2 o;
        o.x = pk4(v[0],v[1],v[2],v[3]); o.y = pk4(v[4],v[5],v[6],v[7]);
        *reinterpret_cast<uint2*>(&W2F[((s*4 + w)*2 + (q >> 1))*1024 + l*16 + (q & 1)*8]) = o;
    } else {
        // ---- W2GF (group cols, scaled x16): 256 blocks, each (s,w) x 16 g's
        int b = bid - LBLK - 128;           // 0..255
        int sw = b & 63, gq = b >> 6;       // gq = g-quarter 0..3
        int s = sw >> 2, w = sw & 3;
        unsigned short (*lds)[640] = (unsigned short(*)[640])smem;
        int k0 = 128*s + 32*w;
        for (int idx = t; idx < 32*640; idx += 256) {
            int kk = idx / 640, c = idx - kk*640;
            lds[kk][c] = bf16bits(16.f * W2[(size_t)(k0 + kk) * OUTD + NK + c]);
        }
        __syncthreads();
        for (int g = gq*16 + (t >> 6); g < gq*16 + 16; g += 4) {
            float v[8];
            #pragma unroll
            for (int bb = 0; bb < 8; ++bb)
                v[bb] = (lr < YD) ? bff(lds[8*lg + bb][10*g + lr]) : 0.f;
            uint2 o;
            o.x = pk4(v[0],v[1],v[2],v[3]); o.y = pk4(v[4],v[5],v[6],v[7]);
            *reinterpret_cast<uint2*>(&W2GF[(((g*16 + s)*4 + w) << 9) + l*8]) = o;
        }
    }
}

// ---------------- kB: scatter (needs completed labels+counts) ----------------
__global__ __launch_bounds__(256) void k_b(const int* __restrict__ labels,
                                           const int* __restrict__ counts,
                                           int* __restrict__ cursor,      // zero-based
                                           int* __restrict__ perm) {
    __shared__ int lh[NK], lbase[NK];
    int t = threadIdx.x, bid = blockIdx.x;
    if (t < NK) lh[t] = 0;
    __syncthreads();
    int i = bid * 256 + t;
    int lab = labels[i];
    int rank = atomicAdd(&lh[lab], 1);
    __syncthreads();
    if (t < NK) {
        int c = counts[t];
        int s = c;
        #pragma unroll
        for (int d = 1; d < 64; d <<= 1) {
            int v = __shfl_up(s, d);
            if (t >= d) s += v;
        }
        int offs = s - c;
        if (lh[t] > 0) lbase[t] = offs + atomicAdd(&cursor[t], lh[t]);
    }
    __syncthreads();
    perm[lbase[lab] + rank] = i;
}

// per-slab weight registers: 5 asm-forced loads, 18 VGPRs per set
struct WR { uint4 w0, w1, q0, q1; uint2 qg; };

__device__ __forceinline__ void loadw_asm(WR& r, int s_,
                                          const unsigned char* __restrict__ W1F,
                                          const unsigned char* __restrict__ W2F,
                                          const unsigned char* __restrict__ W2GF,
                                          int g, int w, int l) {
    const unsigned char* a0 = W1F + (s_*4 + w)*2048 + l*16;
    const unsigned char* a1 = a0 + 1024;
    const unsigned char* b0 = W2F + (s_*4 + w)*2048 + l*16;
    const unsigned char* b1 = b0 + 1024;
    const unsigned char* c0 = W2GF + (((g*16 + s_)*4 + w) << 9) + l*8;
    asm volatile("global_load_dwordx4 %0, %1, off" : "=&v"(r.w0) : "v"(a0));
    asm volatile("global_load_dwordx4 %0, %1, off" : "=&v"(r.w1) : "v"(a1));
    asm volatile("global_load_dwordx4 %0, %1, off" : "=&v"(r.q0) : "v"(b0));
    asm volatile("global_load_dwordx4 %0, %1, off" : "=&v"(r.q1) : "v"(b1));
    asm volatile("global_load_dwordx2 %0, %1, off" : "=&v"(r.qg) : "v"(c0));
}
#define WAIT5() do { asm volatile("s_waitcnt vmcnt(5)" ::: "memory"); \
                     __builtin_amdgcn_sched_barrier(0); } while (0)
#define DRAIN() do { asm volatile("s_waitcnt vmcnt(0)" ::: "memory"); \
                     __builtin_amdgcn_sched_barrier(0); } while (0)

union U4 { uint4 q; long long l2[2]; };
union U2 { uint2 u; long long ll; };

// slab body with in-register bpermute h exchange (R22, verified best)
__device__ __forceinline__ void slab_body(const WR& r,
                                          const U2 (&xf)[4][2], f32x4_t (&acc2)[4][5],
                                          int idx0, int idx1, bool lo) {
    U4 w0, w1, q0, q1; w0.q = r.w0; w1.q = r.w1; q0.q = r.q0; q1.q = r.q1;
    U2 qg; qg.u = r.qg;
    #pragma unroll
    for (int mt = 0; mt < 4; ++mt) {
        f32x4_t h0 = {0.f, 0.f, 0.f, 0.f}, h1 = {0.f, 0.f, 0.f, 0.f};
        h0 = MFMA8(w0.l2[0], xf[mt][0].ll, h0);
        h0 = MFMA8(w0.l2[1], xf[mt][1].ll, h0);
        h1 = MFMA8(w1.l2[0], xf[mt][0].ll, h1);
        h1 = MFMA8(w1.l2[1], xf[mt][1].ll, h1);
        int h0w = pk4(fmaxf(h0[0],0.f), fmaxf(h0[1],0.f), fmaxf(h0[2],0.f), fmaxf(h0[3],0.f));
        int h1w = pk4(fmaxf(h1[0],0.f), fmaxf(h1[1],0.f), fmaxf(h1[2],0.f), fmaxf(h1[3],0.f));
        int p00 = __builtin_amdgcn_ds_bpermute(idx0, h0w);
        int p01 = __builtin_amdgcn_ds_bpermute(idx1, h0w);
        int p10 = __builtin_amdgcn_ds_bpermute(idx0, h1w);
        int p11 = __builtin_amdgcn_ds_bpermute(idx1, h1w);
        U2 a2;
        a2.u.x = lo ? (unsigned int)p00 : (unsigned int)p10;
        a2.u.y = lo ? (unsigned int)p01 : (unsigned int)p11;
        acc2[mt][0] = MFMA8(q0.l2[0], a2.ll, acc2[mt][0]);
        acc2[mt][1] = MFMA8(q0.l2[1], a2.ll, acc2[mt][1]);
        acc2[mt][2] = MFMA8(q1.l2[0], a2.ll, acc2[mt][2]);
        acc2[mt][3] = MFMA8(q1.l2[1], a2.ll, acc2[mt][3]);
        acc2[mt][4] = MFMA8(qg.ll,    a2.ll, acc2[mt][4]);
    }
}

// ---------------- fused + in-kernel finalize (ticket; no threadfence) ------
__global__ __launch_bounds__(256, 2) void k_fused(const float* __restrict__ x,
                                                  const unsigned char* __restrict__ W1F,
                                                  const unsigned char* __restrict__ W2F,
                                                  const unsigned char* __restrict__ W2GF,
                                                  const float* __restrict__ b2,
                                                  const float* __restrict__ y,
                                                  const float* __restrict__ centers,
                                                  const int* __restrict__ counts,
                                                  const int* __restrict__ perm,
                                                  float* __restrict__ accum,
                                                  int* __restrict__ ticket,
                                                  float* __restrict__ out) {
    __shared__ __align__(16) union {
        unsigned char xb[TS][80];   // fp8 x tile (gather phase)
        float o[TS][84];            // epilogue overlay
    } u;
    __shared__ int   rows_s[TS];
    __shared__ int   dsc[3];   // g, off, nrows

    int phys = blockIdx.x, t = threadIdx.x;
    int bid  = (phys & 7) * (MAXT / 8) + (phys >> 3);   // XCD chunk swizzle (bijective)
    int l  = t & 63;
    int w  = t >> 6;
    int lr = l & 15;
    int lg = l >> 4;

    // in-block tile descriptor: wave 0 scans counts
    if (t == 0) dsc[2] = 0;
    if (t < 64) {
        int c = counts[t];
        int ntm = (c + TS - 1) / TS;
        int sc = c, st = ntm;
        #pragma unroll
        for (int d = 1; d < 64; d <<= 1) {
            int vc = __shfl_up(sc, d);
            int vt = __shfl_up(st, d);
            if (t >= d) { sc += vc; st += vt; }
        }
        int offc  = sc - c;
        int tbase = st - ntm;
        if (bid >= tbase && bid < tbase + ntm) {
            int k = bid - tbase;
            dsc[0] = t;
            dsc[1] = offc + TS * k;
            dsc[2] = min(TS, c - TS * k);
        }
    }
    __syncthreads();
    int g = dsc[0], off = dsc[1], nrows = dsc[2];

    if (nrows == 0) {
        if (t == 0) {
            int old = atomicAdd(ticket, 1);
            if (old == MAXT - 1) {
                float ce = atomicAdd(&accum[0], 0.f);
                float ms = atomicAdd(&accum[1], 0.f);
                out[0] = ce / (float)B_N + 100.f * ms / ((float)B_N * (float)YD);
            }
        }
        return;
    }

    if (t < TS) rows_s[t] = (t < nrows) ? perm[off + t] : -1;
    __syncthreads();

    // gather x rows -> LDS fp8; col 60 = 1.0 (bias lane, e4m3 0x38), 61..79 = 0
    {
        int c4 = t & 15;
        #pragma unroll
        for (int it = 0; it < 4; ++it) {
            int r = 16 * it + (t >> 4);
            int row = rows_s[r];
            if (c4 < 15) {
                int pk = 0;
                if (row >= 0) {
                    float4 v = *reinterpret_cast<const float4*>(&x[(size_t)row * XD + 4 * c4]);
                    pk = pk4(v.x, v.y, v.z, v.w);
                }
                *reinterpret_cast<unsigned int*>(&u.xb[r][4 * c4]) = (unsigned int)pk;
            } else {
                *reinterpret_cast<unsigned int*>(&u.xb[r][60]) = (row >= 0) ? 0x00000038u : 0u;
                uint4 z = {0, 0, 0, 0};
                *reinterpret_cast<uint4*>(&u.xb[r][64]) = z;
            }
        }
    }
    __syncthreads();

    U2 xf[4][2];
    #pragma unroll
    for (int mt = 0; mt < 4; ++mt)
        #pragma unroll
        for (int ks = 0; ks < 2; ++ks)
            xf[mt][ks].u = *reinterpret_cast<const uint2*>(&u.xb[16*mt + lr][32*ks + 8*lg]);

    f32x4_t acc2[4][5];
    #pragma unroll
    for (int mt = 0; mt < 4; ++mt)
        #pragma unroll
        for (int nt = 0; nt < 5; ++nt) acc2[mt][nt] = (f32x4_t){0.f, 0.f, 0.f, 0.f};

    // bpermute indices (byte addressing: 4 * src_lane)
    int idx0 = 4 * (16 * ((2 * lg) & 3) + lr);
    int idx1 = idx0 + 64;
    bool lo  = (lg < 2);

    // depth-2 pipeline: asm loads + counted vmcnt
    WR rA, rB;
    loadw_asm(rA, 0, W1F, W2F, W2GF, g, w, l);
    #pragma unroll 1
    for (int s = 0; s < HID / 128; s += 2) {
        loadw_asm(rB, s + 1, W1F, W2F, W2GF, g, w, l);
        WAIT5();
        slab_body(rA, xf, acc2, idx0, idx1, lo);
        loadw_asm(rA, (s + 2 < 16) ? s + 2 : 0, W1F, W2F, W2GF, g, w, l);
        WAIT5();
        slab_body(rB, xf, acc2, idx0, idx1, lo);
    }
    DRAIN();           // dead in-flight tail loads complete before reg reuse
    __syncthreads();   // all xb reads done before overlaying u.o

    // epilogue: sum 4 K-partials (x 1/256 weight prescale), bias in phase 0
    const float inv = 1.f / 256.f;
    for (int wv = 0; wv < 4; ++wv) {
        if (w == wv) {
            #pragma unroll
            for (int mt = 0; mt < 4; ++mt)
                #pragma unroll
                for (int nt = 0; nt < 5; ++nt) {
                    float4 v;
                    v.x = acc2[mt][nt][0] * inv; v.y = acc2[mt][nt][1] * inv;
                    v.z = acc2[mt][nt][2] * inv; v.w = acc2[mt][nt][3] * inv;
                    float4* pp = reinterpret_cast<float4*>(&u.o[16*mt + lr][16*nt + 4*lg]);
                    if (wv == 0) {
                        float bx, by, bz, bw;
                        if (nt < 4) {
                            int c = 16*nt + 4*lg;
                            bx = b2[c]; by = b2[c+1]; bz = b2[c+2]; bw = b2[c+3];
                        } else {
                            int c = 4*lg;
                            bx = (c   < YD) ? b2[NK + g*YD + c  ] : 0.f;
                            by = (c+1 < YD) ? b2[NK + g*YD + c+1] : 0.f;
                            bz = (c+2 < YD) ? b2[NK + g*YD + c+2] : 0.f;
                            bw = (c+3 < YD) ? b2[NK + g*YD + c+3] : 0.f;
                        }
                        v.x += bx; v.y += by; v.z += bz; v.w += bw;
                        *pp = v;
                    } else {
                        float4 cur = *pp;
                        cur.x += v.x; cur.y += v.y; cur.z += v.z; cur.w += v.w;
                        *pp = cur;
                    }
                }
        }
        __syncthreads();
    }

    // per-row loss; rows 0..63 == wave 0 -> shuffle-reduce, one atomic pair
    if (t < TS) {
        float ce_v = 0.f, mse_v = 0.f;
        if (t < nrows) {
            float m = -1e30f;
            for (int c = 0; c < NK; ++c) m = fmaxf(m, u.o[t][c]);
            float s2 = 0.f;
            for (int c = 0; c < NK; ++c) s2 += expf(u.o[t][c] - m);
            float lse = m + logf(s2);
            ce_v = lse - u.o[t][g];
            int row = rows_s[t];
            #pragma unroll
            for (int j = 0; j < YD; ++j) {
                float tr = y[row * YD + j] - centers[g * YD + j];
                float d  = tr - u.o[t][NK + j];
                mse_v += d * d;
            }
        }
        #pragma unroll
        for (int d = 32; d > 0; d >>= 1) {
            ce_v  += __shfl_down(ce_v, d);
            mse_v += __shfl_down(mse_v, d);
        }
        if (t == 0) {
            atomicAdd(&accum[0], ce_v);
            atomicAdd(&accum[1], mse_v);
            asm volatile("s_waitcnt vmcnt(0)" ::: "memory");
            int old = atomicAdd(ticket, 1);
            if (old == MAXT - 1) {
                float ce = atomicAdd(&accum[0], 0.f);
                float ms = atomicAdd(&accum[1], 0.f);
                out[0] = ce / (float)B_N + 100.f * ms / ((float)B_N * (float)YD);
            }
        }
    }
}

extern "C" void kernel_launch(void* const* d_in, const int* in_sizes, int n_in,
                              void* d_out, int out_size, void* d_ws, size_t ws_size,
                              hipStream_t stream) {
    const float* x       = (const float*)d_in[0];
    const float* y       = (const float*)d_in[1];
    const float* centers = (const float*)d_in[2];
    const float* W1      = (const float*)d_in[3];
    const float* b1      = (const float*)d_in[4];
    const float* W2      = (const float*)d_in[5];
    const float* b2      = (const float*)d_in[6];

    char* ws = (char*)d_ws;
    float* accum  = (float*)ws;                        // 2 f32 @ 0
    int* ticket   = (int*)(ws + 128);
    int* counts   = (int*)(ws + 256);                  // 64 ints
    int* cursor   = (int*)(ws + 768);                  // 64 ints (zero-based)
    char* ws2     = ws + 4096;
    int* labels   = (int*)ws2;                                   // 128 KB
    int* perm     = (int*)(ws2 + 131072);                        // 128 KB
    unsigned char* W1F  = (unsigned char*)(ws2 + 262144);        // 128 KB
    unsigned char* W2F  = (unsigned char*)(ws2 + 393216);        // 128 KB
    unsigned char* W2GF = (unsigned char*)(ws2 + 524288);        // 2 MB

    hipMemsetAsync(ws, 0, 1024, stream);   // zero accum + ticket + counts + cursor
    k_a     <<<LBLK + 384, 256, 0, stream>>>(y, centers, W1, b1, W2,
                                             labels, counts, W1F, W2F, W2GF);
    k_b     <<<B_N / 256, 256, 0, stream>>>(labels, counts, cursor, perm);
    k_fused <<<MAXT, 256, 0, stream>>>(x, W1F, W2F, W2GF, b2, y, centers,
                                       counts, perm, accum, ticket, (float*)d_out);
}

// Round 25
// 61.366 us; speedup vs baseline: 1.2163x; 1.0323x over previous
//
#include <hip/hip_runtime.h>
#include <hip/hip_bf16.h>
#include <math.h>

#define B_N    32768
#define XD     60
#define YD     10
#define NK     64
#define HID    2048
#define OUTD   704   // NK + NK*YD
#define TS     64    // rows per tile
#define MAXT   576   // >= 512 full tiles + 64 partials; divisible by 8 (XCD swizzle)

#define LBLK   128   // label blocks (B/256)

typedef float f32x4_t __attribute__((ext_vector_type(4)));

#define MFMA8(a, b, c) __builtin_amdgcn_mfma_f32_16x16x32_fp8_fp8(a, b, c, 0, 0, 0)

__device__ __forceinline__ unsigned short bf16bits(float f) {
    __hip_bfloat16 h = __float2bfloat16(f);
    return *reinterpret_cast<unsigned short*>(&h);
}
__device__ __forceinline__ float bff(unsigned short b) {
    unsigned int u = ((unsigned int)b) << 16;
    return __uint_as_float(u);
}
// pack 4 floats -> 4 e4m3 bytes (RNE, saturating) via HW cvt
__device__ __forceinline__ int pk4(float a, float b, float c, float d) {
    int p = __builtin_amdgcn_cvt_pk_fp8_f32(a, b, 0, false);
    return __builtin_amdgcn_cvt_pk_fp8_f32(c, d, p, true);
}

// ---------------- kA: labels+per-block hist (0..127) || W1F (128..191)
// || W2F (192..255) || W2GF (256..511). No pre-zeroed memory needed.
__global__ __launch_bounds__(256) void k_a(const float* __restrict__ y,
                                           const float* __restrict__ centers,
                                           const float* __restrict__ W1,
                                           const float* __restrict__ b1,
                                           const float* __restrict__ W2,
                                           int* __restrict__ labels,
                                           int* __restrict__ hist,
                                           unsigned char* __restrict__ W1F,
                                           unsigned char* __restrict__ W2F,
                                           unsigned char* __restrict__ W2GF) {
    __shared__ __align__(16) char smem[40960];
    int bid = blockIdx.x, t = threadIdx.x;
    int l  = t & 63;
    int lr = l & 15;
    int lg = l >> 4;

    if (bid < LBLK) {
        float* cs = (float*)smem; float* sc = cs + 640; int* lh = (int*)(cs + 704);
        for (int i = t; i < NK * YD; i += 256) cs[i] = centers[i];
        if (t < NK) lh[t] = 0;
        __syncthreads();
        if (t < NK) { float s = 0.f; for (int j = 0; j < YD; ++j) { float v = cs[t*YD+j]; s += v*v; } sc[t] = s; }
        __syncthreads();
        int i = bid * 256 + t;
        float ly[YD]; float sy = 0.f;
        for (int j = 0; j < YD; ++j) { ly[j] = y[i*YD+j]; sy += ly[j]*ly[j]; }
        float best = 1e30f; int lab = 0;
        for (int k = 0; k < NK; ++k) {
            float dot = 0.f;
            #pragma unroll
            for (int j = 0; j < YD; ++j) dot += ly[j] * cs[k*YD+j];
            float d = sy - 2.f*dot + sc[k];
            if (d < best) { best = d; lab = k; }
        }
        labels[i] = lab;
        atomicAdd(&lh[lab], 1);
        __syncthreads();
        if (t < NK) hist[bid * NK + t] = lh[t];   // plain store (no global atomics)
    } else if (bid < LBLK + 64) {
        // ---- W1F (scaled x16, b1 folded at k=60)
        int b = bid - LBLK, s = b >> 2, w = b & 3;
        unsigned short (*lds)[32] = (unsigned short(*)[32])smem;
        int n0 = 128*s + 32*w;
        for (int idx = t; idx < 64*32; idx += 256) {
            int kk = idx >> 5, c = idx & 31;
            float v = (kk < XD) ? 16.f * W1[(size_t)(YD + kk) * HID + n0 + c]
                                : ((kk == XD) ? 16.f * b1[n0 + c] : 0.f);
            lds[kk][c] = bf16bits(v);
        }
        __syncthreads();
        if (t < 128) {
            int n2 = (t >> 6) & 1;
            float v[16];
            #pragma unroll
            for (int ks = 0; ks < 2; ++ks)
                #pragma unroll
                for (int bb = 0; bb < 8; ++bb)
                    v[8*ks + bb] = bff(lds[32*ks + 8*lg + bb][16*n2 + lr]);
            uint4 o;
            o.x = pk4(v[0],v[1],v[2],v[3]);   o.y = pk4(v[4],v[5],v[6],v[7]);
            o.z = pk4(v[8],v[9],v[10],v[11]); o.w = pk4(v[12],v[13],v[14],v[15]);
            *reinterpret_cast<uint4*>(&W1F[((s*4 + w)*2 + n2)*1024 + l*16]) = o;
        }
    } else if (bid < LBLK + 128) {
        // ---- W2F (logit cols, scaled x16)
        int b = bid - LBLK - 64, s = b >> 2, w = b & 3;
        unsigned short (*lds)[64] = (unsigned short(*)[64])smem;
        int k0 = 128*s + 32*w;
        for (int idx = t; idx < 32*64; idx += 256) {
            int kk = idx >> 6, c = idx & 63;
            lds[kk][c] = bf16bits(16.f * W2[(size_t)(k0 + kk) * OUTD + c]);
        }
        __syncthreads();
        int q = t >> 6;
        float v[8];
        #pragma unroll
        for (int bb = 0; bb < 8; ++bb) v[bb] = bff(lds[8*lg + bb][16*q + lr]);
        uint2 o;
        o.x = pk4(v[0],v[1],v[2],v[3]); o.y = pk4(v[4],v[5],v[6],v[7]);
        *reinterpret_cast<uint2*>(&W2F[((s*4 + w)*2 + (q >> 1))*1024 + l*16 + (q & 1)*8]) = o;
    } else {
        // ---- W2GF (group cols, scaled x16): 256 blocks, each (s,w) x 16 g's
        int b = bid - LBLK - 128;           // 0..255
        int sw = b & 63, gq = b >> 6;       // gq = g-quarter 0..3
        int s = sw >> 2, w = sw & 3;
        unsigned short (*lds)[640] = (unsigned short(*)[640])smem;
        int k0 = 128*s + 32*w;
        for (int idx = t; idx < 32*640; idx += 256) {
            int kk = idx / 640, c = idx - kk*640;
            lds[kk][c] = bf16bits(16.f * W2[(size_t)(k0 + kk) * OUTD + NK + c]);
        }
        __syncthreads();
        for (int g = gq*16 + (t >> 6); g < gq*16 + 16; g += 4) {
            float v[8];
            #pragma unroll
            for (int bb = 0; bb < 8; ++bb)
                v[bb] = (lr < YD) ? bff(lds[8*lg + bb][10*g + lr]) : 0.f;
            uint2 o;
            o.x = pk4(v[0],v[1],v[2],v[3]); o.y = pk4(v[4],v[5],v[6],v[7]);
            *reinterpret_cast<uint2*>(&W2GF[(((g*16 + s)*4 + w) << 9) + l*8]) = o;
        }
    }
}

// ---------------- kB: scatter from per-block histograms (no cursor atomics).
// Block bid base for label t = group_offset(t) + sum_{b<bid} hist[b][t].
// Block 0 also publishes counts and zeroes accum/ticket for k_fused.
__global__ __launch_bounds__(256) void k_b(const int* __restrict__ labels,
                                           const int* __restrict__ hist,
                                           int* __restrict__ counts,
                                           int* __restrict__ perm,
                                           float* __restrict__ accum,
                                           int* __restrict__ ticket) {
    __shared__ int lh[NK], lbase[NK];
    int t = threadIdx.x, bid = blockIdx.x;
    if (t < NK) lh[t] = 0;
    __syncthreads();
    int i = bid * 256 + t;
    int lab = labels[i];
    int rank = atomicAdd(&lh[lab], 1);
    if (t < NK) {
        int tot = 0, pre = 0;
        for (int b = 0; b < LBLK; ++b) {
            int h = hist[b * NK + t];
            pre += (b < bid) ? h : 0;
            tot += h;
        }
        int s = tot;
        #pragma unroll
        for (int d = 1; d < 64; d <<= 1) {
            int v = __shfl_up(s, d);
            if (t >= d) s += v;
        }
        lbase[t] = (s - tot) + pre;   // group offset + cross-block prefix
        if (bid == 0) counts[t] = tot;
    }
    if (bid == 0 && t == 64) { accum[0] = 0.f; accum[1] = 0.f; }
    if (bid == 0 && t == 65) { *ticket = 0; }
    __syncthreads();
    perm[lbase[lab] + rank] = i;
}

// per-slab weight registers: 5 asm-forced loads, 18 VGPRs per set
struct WR { uint4 w0, w1, q0, q1; uint2 qg; };

__device__ __forceinline__ void loadw_asm(WR& r, int s_,
                                          const unsigned char* __restrict__ W1F,
                                          const unsigned char* __restrict__ W2F,
                                          const unsigned char* __restrict__ W2GF,
                                          int g, int w, int l) {
    const unsigned char* a0 = W1F + (s_*4 + w)*2048 + l*16;
    const unsigned char* a1 = a0 + 1024;
    const unsigned char* b0 = W2F + (s_*4 + w)*2048 + l*16;
    const unsigned char* b1 = b0 + 1024;
    const unsigned char* c0 = W2GF + (((g*16 + s_)*4 + w) << 9) + l*8;
    asm volatile("global_load_dwordx4 %0, %1, off" : "=&v"(r.w0) : "v"(a0));
    asm volatile("global_load_dwordx4 %0, %1, off" : "=&v"(r.w1) : "v"(a1));
    asm volatile("global_load_dwordx4 %0, %1, off" : "=&v"(r.q0) : "v"(b0));
    asm volatile("global_load_dwordx4 %0, %1, off" : "=&v"(r.q1) : "v"(b1));
    asm volatile("global_load_dwordx2 %0, %1, off" : "=&v"(r.qg) : "v"(c0));
}
#define WAIT5() do { asm volatile("s_waitcnt vmcnt(5)" ::: "memory"); \
                     __builtin_amdgcn_sched_barrier(0); } while (0)
#define DRAIN() do { asm volatile("s_waitcnt vmcnt(0)" ::: "memory"); \
                     __builtin_amdgcn_sched_barrier(0); } while (0)

union U4 { uint4 q; long long l2[2]; };
union U2 { uint2 u; long long ll; };

// slab body with in-register bpermute h exchange (R22/R24, verified best)
__device__ __forceinline__ void slab_body(const WR& r,
                                          const U2 (&xf)[4][2], f32x4_t (&acc2)[4][5],
                                          int idx0, int idx1, bool lo) {
    U4 w0, w1, q0, q1; w0.q = r.w0; w1.q = r.w1; q0.q = r.q0; q1.q = r.q1;
    U2 qg; qg.u = r.qg;
    #pragma unroll
    for (int mt = 0; mt < 4; ++mt) {
        f32x4_t h0 = {0.f, 0.f, 0.f, 0.f}, h1 = {0.f, 0.f, 0.f, 0.f};
        h0 = MFMA8(w0.l2[0], xf[mt][0].ll, h0);
        h0 = MFMA8(w0.l2[1], xf[mt][1].ll, h0);
        h1 = MFMA8(w1.l2[0], xf[mt][0].ll, h1);
        h1 = MFMA8(w1.l2[1], xf[mt][1].ll, h1);
        int h0w = pk4(fmaxf(h0[0],0.f), fmaxf(h0[1],0.f), fmaxf(h0[2],0.f), fmaxf(h0[3],0.f));
        int h1w = pk4(fmaxf(h1[0],0.f), fmaxf(h1[1],0.f), fmaxf(h1[2],0.f), fmaxf(h1[3],0.f));
        int p00 = __builtin_amdgcn_ds_bpermute(idx0, h0w);
        int p01 = __builtin_amdgcn_ds_bpermute(idx1, h0w);
        int p10 = __builtin_amdgcn_ds_bpermute(idx0, h1w);
        int p11 = __builtin_amdgcn_ds_bpermute(idx1, h1w);
        U2 a2;
        a2.u.x = lo ? (unsigned int)p00 : (unsigned int)p10;
        a2.u.y = lo ? (unsigned int)p01 : (unsigned int)p11;
        acc2[mt][0] = MFMA8(q0.l2[0], a2.ll, acc2[mt][0]);
        acc2[mt][1] = MFMA8(q0.l2[1], a2.ll, acc2[mt][1]);
        acc2[mt][2] = MFMA8(q1.l2[0], a2.ll, acc2[mt][2]);
        acc2[mt][3] = MFMA8(q1.l2[1], a2.ll, acc2[mt][3]);
        acc2[mt][4] = MFMA8(qg.ll,    a2.ll, acc2[mt][4]);
    }
}

// ---------------- fused + in-kernel finalize (ticket; no threadfence) ------
__global__ __launch_bounds__(256, 2) void k_fused(const float* __restrict__ x,
                                                  const unsigned char* __restrict__ W1F,
                                                  const unsigned char* __restrict__ W2F,
                                                  const unsigned char* __restrict__ W2GF,
                                                  const float* __restrict__ b2,
                                                  const float* __restrict__ y,
                                                  const float* __restrict__ centers,
                                                  const int* __restrict__ counts,
                                                  const int* __restrict__ perm,
                                                  float* __restrict__ accum,
                                                  int* __restrict__ ticket,
                                                  float* __restrict__ out) {
    __shared__ __align__(16) union {
        unsigned char xb[TS][80];   // fp8 x tile (gather phase)
        float o[TS][84];            // epilogue overlay
    } u;
    __shared__ int   rows_s[TS];
    __shared__ int   dsc[3];   // g, off, nrows

    int phys = blockIdx.x, t = threadIdx.x;
    int bid  = (phys & 7) * (MAXT / 8) + (phys >> 3);   // XCD chunk swizzle (bijective)
    int l  = t & 63;
    int w  = t >> 6;
    int lr = l & 15;
    int lg = l >> 4;

    // in-block tile descriptor: wave 0 scans counts
    if (t == 0) dsc[2] = 0;
    if (t < 64) {
        int c = counts[t];
        int ntm = (c + TS - 1) / TS;
        int sc = c, st = ntm;
        #pragma unroll
        for (int d = 1; d < 64; d <<= 1) {
            int vc = __shfl_up(sc, d);
            int vt = __shfl_up(st, d);
            if (t >= d) { sc += vc; st += vt; }
        }
        int offc  = sc - c;
        int tbase = st - ntm;
        if (bid >= tbase && bid < tbase + ntm) {
            int k = bid - tbase;
            dsc[0] = t;
            dsc[1] = offc + TS * k;
            dsc[2] = min(TS, c - TS * k);
        }
    }
    __syncthreads();
    int g = dsc[0], off = dsc[1], nrows = dsc[2];

    if (nrows == 0) {
        if (t == 0) {
            int old = atomicAdd(ticket, 1);
            if (old == MAXT - 1) {
                float ce = atomicAdd(&accum[0], 0.f);
                float ms = atomicAdd(&accum[1], 0.f);
                out[0] = ce / (float)B_N + 100.f * ms / ((float)B_N * (float)YD);
            }
        }
        return;
    }

    if (t < TS) rows_s[t] = (t < nrows) ? perm[off + t] : -1;
    __syncthreads();

    // gather x rows -> LDS fp8; col 60 = 1.0 (bias lane, e4m3 0x38), 61..79 = 0
    {
        int c4 = t & 15;
        #pragma unroll
        for (int it = 0; it < 4; ++it) {
            int r = 16 * it + (t >> 4);
            int row = rows_s[r];
            if (c4 < 15) {
                int pk = 0;
                if (row >= 0) {
                    float4 v = *reinterpret_cast<const float4*>(&x[(size_t)row * XD + 4 * c4]);
                    pk = pk4(v.x, v.y, v.z, v.w);
                }
                *reinterpret_cast<unsigned int*>(&u.xb[r][4 * c4]) = (unsigned int)pk;
            } else {
                *reinterpret_cast<unsigned int*>(&u.xb[r][60]) = (row >= 0) ? 0x00000038u : 0u;
                uint4 z = {0, 0, 0, 0};
                *reinterpret_cast<uint4*>(&u.xb[r][64]) = z;
            }
        }
    }
    __syncthreads();

    U2 xf[4][2];
    #pragma unroll
    for (int mt = 0; mt < 4; ++mt)
        #pragma unroll
        for (int ks = 0; ks < 2; ++ks)
            xf[mt][ks].u = *reinterpret_cast<const uint2*>(&u.xb[16*mt + lr][32*ks + 8*lg]);

    f32x4_t acc2[4][5];
    #pragma unroll
    for (int mt = 0; mt < 4; ++mt)
        #pragma unroll
        for (int nt = 0; nt < 5; ++nt) acc2[mt][nt] = (f32x4_t){0.f, 0.f, 0.f, 0.f};

    // bpermute indices (byte addressing: 4 * src_lane)
    int idx0 = 4 * (16 * ((2 * lg) & 3) + lr);
    int idx1 = idx0 + 64;
    bool lo  = (lg < 2);

    // depth-2 pipeline: asm loads + counted vmcnt
    WR rA, rB;
    loadw_asm(rA, 0, W1F, W2F, W2GF, g, w, l);
    #pragma unroll 1
    for (int s = 0; s < HID / 128; s += 2) {
        loadw_asm(rB, s + 1, W1F, W2F, W2GF, g, w, l);
        WAIT5();
        slab_body(rA, xf, acc2, idx0, idx1, lo);
        loadw_asm(rA, (s + 2 < 16) ? s + 2 : 0, W1F, W2F, W2GF, g, w, l);
        WAIT5();
        slab_body(rB, xf, acc2, idx0, idx1, lo);
    }
    DRAIN();           // dead in-flight tail loads complete before reg reuse
    __syncthreads();   // all xb reads done before overlaying u.o

    // epilogue: sum 4 K-partials (x 1/256 weight prescale), bias in phase 0
    const float inv = 1.f / 256.f;
    for (int wv = 0; wv < 4; ++wv) {
        if (w == wv) {
            #pragma unroll
            for (int mt = 0; mt < 4; ++mt)
                #pragma unroll
                for (int nt = 0; nt < 5; ++nt) {
                    float4 v;
                    v.x = acc2[mt][nt][0] * inv; v.y = acc2[mt][nt][1] * inv;
                    v.z = acc2[mt][nt][2] * inv; v.w = acc2[mt][nt][3] * inv;
                    float4* pp = reinterpret_cast<float4*>(&u.o[16*mt + lr][16*nt + 4*lg]);
                    if (wv == 0) {
                        float bx, by, bz, bw;
                        if (nt < 4) {
                            int c = 16*nt + 4*lg;
                            bx = b2[c]; by = b2[c+1]; bz = b2[c+2]; bw = b2[c+3];
                        } else {
                            int c = 4*lg;
                            bx = (c   < YD) ? b2[NK + g*YD + c  ] : 0.f;
                            by = (c+1 < YD) ? b2[NK + g*YD + c+1] : 0.f;
                            bz = (c+2 < YD) ? b2[NK + g*YD + c+2] : 0.f;
                            bw = (c+3 < YD) ? b2[NK + g*YD + c+3] : 0.f;
                        }
                        v.x += bx; v.y += by; v.z += bz; v.w += bw;
                        *pp = v;
                    } else {
                        float4 cur = *pp;
                        cur.x += v.x; cur.y += v.y; cur.z += v.z; cur.w += v.w;
                        *pp = cur;
                    }
                }
        }
        __syncthreads();
    }

    // per-row loss; rows 0..63 == wave 0 -> shuffle-reduce, one atomic pair
    if (t < TS) {
        float ce_v = 0.f, mse_v = 0.f;
        if (t < nrows) {
            float m = -1e30f;
            for (int c = 0; c < NK; ++c) m = fmaxf(m, u.o[t][c]);
            float s2 = 0.f;
            for (int c = 0; c < NK; ++c) s2 += expf(u.o[t][c] - m);
            float lse = m + logf(s2);
            ce_v = lse - u.o[t][g];
            int row = rows_s[t];
            #pragma unroll
            for (int j = 0; j < YD; ++j) {
                float tr = y[row * YD + j] - centers[g * YD + j];
                float d  = tr - u.o[t][NK + j];
                mse_v += d * d;
            }
        }
        #pragma unroll
        for (int d = 32; d > 0; d >>= 1) {
            ce_v  += __shfl_down(ce_v, d);
            mse_v += __shfl_down(mse_v, d);
        }
        if (t == 0) {
            atomicAdd(&accum[0], ce_v);
            atomicAdd(&accum[1], mse_v);
            asm volatile("s_waitcnt vmcnt(0)" ::: "memory");
            int old = atomicAdd(ticket, 1);
            if (old == MAXT - 1) {
                float ce = atomicAdd(&accum[0], 0.f);
                float ms = atomicAdd(&accum[1], 0.f);
                out[0] = ce / (float)B_N + 100.f * ms / ((float)B_N * (float)YD);
            }
        }
    }
}

extern "C" void kernel_launch(void* const* d_in, const int* in_sizes, int n_in,
                              void* d_out, int out_size, void* d_ws, size_t ws_size,
                              hipStream_t stream) {
    const float* x       = (const float*)d_in[0];
    const float* y       = (const float*)d_in[1];
    const float* centers = (const float*)d_in[2];
    const float* W1      = (const float*)d_in[3];
    const float* b1      = (const float*)d_in[4];
    const float* W2      = (const float*)d_in[5];
    const float* b2      = (const float*)d_in[6];

    char* ws = (char*)d_ws;
    float* accum  = (float*)ws;                        // 2 f32 @ 0 (zeroed by k_b)
    int* ticket   = (int*)(ws + 128);                  // zeroed by k_b
    int* counts   = (int*)(ws + 256);                  // written by k_b
    int* hist     = (int*)(ws + 4096);                 // 128 x 64 ints (32 KB, k_a)
    char* ws2     = ws + 4096 + 32768;
    int* labels   = (int*)ws2;                                   // 128 KB
    int* perm     = (int*)(ws2 + 131072);                        // 128 KB
    unsigned char* W1F  = (unsigned char*)(ws2 + 262144);        // 128 KB
    unsigned char* W2F  = (unsigned char*)(ws2 + 393216);        // 128 KB
    unsigned char* W2GF = (unsigned char*)(ws2 + 524288);        // 2 MB

    k_a     <<<LBLK + 384, 256, 0, stream>>>(y, centers, W1, b1, W2,
                                             labels, hist, W1F, W2F, W2GF);
    k_b     <<<B_N / 256, 256, 0, stream>>>(labels, hist, counts, perm,
                                            accum, ticket);
    k_fused <<<MAXT, 256, 0, stream>>>(x, W1F, W2F, W2GF, b2, y, centers,
                                       counts, perm, accum, ticket, (float*)d_out);
}

// Round 26
// 57.377 us; speedup vs baseline: 1.3008x; 1.0695x over previous
//
#include <hip/hip_runtime.h>
#include <hip/hip_bf16.h>
#include <math.h>

#define B_N    32768
#define XD     60
#define YD     10
#define NK     64
#define HID    2048
#define OUTD   704   // NK + NK*YD
#define TS     64    // rows per tile
#define MAXT   576   // >= 512 full tiles + 64 partials; divisible by 8 (XCD swizzle)

#define LBLK   128   // label blocks (B/256)

typedef float f32x4_t __attribute__((ext_vector_type(4)));

#define MFMA8(a, b, c) __builtin_amdgcn_mfma_f32_16x16x32_fp8_fp8(a, b, c, 0, 0, 0)

__device__ __forceinline__ unsigned short bf16bits(float f) {
    __hip_bfloat16 h = __float2bfloat16(f);
    return *reinterpret_cast<unsigned short*>(&h);
}
__device__ __forceinline__ float bff(unsigned short b) {
    unsigned int u = ((unsigned int)b) << 16;
    return __uint_as_float(u);
}
// pack 4 floats -> 4 e4m3 bytes (RNE, saturating) via HW cvt
__device__ __forceinline__ int pk4(float a, float b, float c, float d) {
    int p = __builtin_amdgcn_cvt_pk_fp8_f32(a, b, 0, false);
    return __builtin_amdgcn_cvt_pk_fp8_f32(c, d, p, true);
}

// ---------------- kA: labels+per-block hist (0..127) || W1F (128..191)
// || W2F (192..255) || W2GF (256..511). No pre-zeroed memory needed.
__global__ __launch_bounds__(256) void k_a(const float* __restrict__ y,
                                           const float* __restrict__ centers,
                                           const float* __restrict__ W1,
                                           const float* __restrict__ b1,
                                           const float* __restrict__ W2,
                                           int* __restrict__ labels,
                                           int* __restrict__ hist,
                                           unsigned char* __restrict__ W1F,
                                           unsigned char* __restrict__ W2F,
                                           unsigned char* __restrict__ W2GF) {
    __shared__ __align__(16) char smem[40960];
    int bid = blockIdx.x, t = threadIdx.x;
    int l  = t & 63;
    int lr = l & 15;
    int lg = l >> 4;

    if (bid < LBLK) {
        float* cs = (float*)smem; float* sc = cs + 640; int* lh = (int*)(cs + 704);
        for (int i = t; i < NK * YD; i += 256) cs[i] = centers[i];
        if (t < NK) lh[t] = 0;
        __syncthreads();
        if (t < NK) { float s = 0.f; for (int j = 0; j < YD; ++j) { float v = cs[t*YD+j]; s += v*v; } sc[t] = s; }
        __syncthreads();
        int i = bid * 256 + t;
        float ly[YD]; float sy = 0.f;
        for (int j = 0; j < YD; ++j) { ly[j] = y[i*YD+j]; sy += ly[j]*ly[j]; }
        float best = 1e30f; int lab = 0;
        for (int k = 0; k < NK; ++k) {
            float dot = 0.f;
            #pragma unroll
            for (int j = 0; j < YD; ++j) dot += ly[j] * cs[k*YD+j];
            float d = sy - 2.f*dot + sc[k];
            if (d < best) { best = d; lab = k; }
        }
        labels[i] = lab;
        atomicAdd(&lh[lab], 1);
        __syncthreads();
        if (t < NK) hist[bid * NK + t] = lh[t];   // plain store (no global atomics)
    } else if (bid < LBLK + 64) {
        // ---- W1F (scaled x16, b1 folded at k=60)
        int b = bid - LBLK, s = b >> 2, w = b & 3;
        unsigned short (*lds)[32] = (unsigned short(*)[32])smem;
        int n0 = 128*s + 32*w;
        for (int idx = t; idx < 64*32; idx += 256) {
            int kk = idx >> 5, c = idx & 31;
            float v = (kk < XD) ? 16.f * W1[(size_t)(YD + kk) * HID + n0 + c]
                                : ((kk == XD) ? 16.f * b1[n0 + c] : 0.f);
            lds[kk][c] = bf16bits(v);
        }
        __syncthreads();
        if (t < 128) {
            int n2 = (t >> 6) & 1;
            float v[16];
            #pragma unroll
            for (int ks = 0; ks < 2; ++ks)
                #pragma unroll
                for (int bb = 0; bb < 8; ++bb)
                    v[8*ks + bb] = bff(lds[32*ks + 8*lg + bb][16*n2 + lr]);
            uint4 o;
            o.x = pk4(v[0],v[1],v[2],v[3]);   o.y = pk4(v[4],v[5],v[6],v[7]);
            o.z = pk4(v[8],v[9],v[10],v[11]); o.w = pk4(v[12],v[13],v[14],v[15]);
            *reinterpret_cast<uint4*>(&W1F[((s*4 + w)*2 + n2)*1024 + l*16]) = o;
        }
    } else if (bid < LBLK + 128) {
        // ---- W2F (logit cols, scaled x16)
        int b = bid - LBLK - 64, s = b >> 2, w = b & 3;
        unsigned short (*lds)[64] = (unsigned short(*)[64])smem;
        int k0 = 128*s + 32*w;
        for (int idx = t; idx < 32*64; idx += 256) {
            int kk = idx >> 6, c = idx & 63;
            lds[kk][c] = bf16bits(16.f * W2[(size_t)(k0 + kk) * OUTD + c]);
        }
        __syncthreads();
        int q = t >> 6;
        float v[8];
        #pragma unroll
        for (int bb = 0; bb < 8; ++bb) v[bb] = bff(lds[8*lg + bb][16*q + lr]);
        uint2 o;
        o.x = pk4(v[0],v[1],v[2],v[3]); o.y = pk4(v[4],v[5],v[6],v[7]);
        *reinterpret_cast<uint2*>(&W2F[((s*4 + w)*2 + (q >> 1))*1024 + l*16 + (q & 1)*8]) = o;
    } else {
        // ---- W2GF (group cols, scaled x16): 256 blocks, each (s,w) x 16 g's.
        // Load ONLY the 160-col slice this block consumes (1x W2 traffic).
        int b = bid - LBLK - 128;           // 0..255
        int sw = b & 63, gq = b >> 6;       // gq = g-quarter 0..3
        int s = sw >> 2, w = sw & 3;
        unsigned short (*lds)[160] = (unsigned short(*)[160])smem;  // [k 0..31][c 0..159]
        int k0 = 128*s + 32*w;
        int c0 = NK + 160*gq;
        for (int idx = t; idx < 32*160; idx += 256) {
            int kk = idx / 160, c = idx - kk*160;
            lds[kk][c] = bf16bits(16.f * W2[(size_t)(k0 + kk) * OUTD + c0 + c]);
        }
        __syncthreads();
        for (int g = gq*16 + (t >> 6); g < gq*16 + 16; g += 4) {
            int gloc = g - gq*16;
            float v[8];
            #pragma unroll
            for (int bb = 0; bb < 8; ++bb)
                v[bb] = (lr < YD) ? bff(lds[8*lg + bb][10*gloc + lr]) : 0.f;
            uint2 o;
            o.x = pk4(v[0],v[1],v[2],v[3]); o.y = pk4(v[4],v[5],v[6],v[7]);
            *reinterpret_cast<uint2*>(&W2GF[(((g*16 + s)*4 + w) << 9) + l*8]) = o;
        }
    }
}

// ---------------- kB: scatter from per-block histograms (no cursor atomics).
// Block 0 also publishes counts and zeroes accum/ticket for k_fused.
__global__ __launch_bounds__(256) void k_b(const int* __restrict__ labels,
                                           const int* __restrict__ hist,
                                           int* __restrict__ counts,
                                           int* __restrict__ perm,
                                           float* __restrict__ accum,
                                           int* __restrict__ ticket) {
    __shared__ int lh[NK], lbase[NK];
    int t = threadIdx.x, bid = blockIdx.x;
    if (t < NK) lh[t] = 0;
    __syncthreads();
    int i = bid * 256 + t;
    int lab = labels[i];
    int rank = atomicAdd(&lh[lab], 1);
    if (t < NK) {
        int tot = 0, pre = 0;
        for (int b = 0; b < LBLK; ++b) {
            int h = hist[b * NK + t];
            pre += (b < bid) ? h : 0;
            tot += h;
        }
        int s = tot;
        #pragma unroll
        for (int d = 1; d < 64; d <<= 1) {
            int v = __shfl_up(s, d);
            if (t >= d) s += v;
        }
        lbase[t] = (s - tot) + pre;   // group offset + cross-block prefix
        if (bid == 0) counts[t] = tot;
    }
    if (bid == 0 && t == 64) { accum[0] = 0.f; accum[1] = 0.f; }
    if (bid == 0 && t == 65) { *ticket = 0; }
    __syncthreads();
    perm[lbase[lab] + rank] = i;
}

// per-slab weight registers: 5 asm-forced loads, 18 VGPRs per set
struct WR { uint4 w0, w1, q0, q1; uint2 qg; };

__device__ __forceinline__ void loadw_asm(WR& r, int s_,
                                          const unsigned char* __restrict__ W1F,
                                          const unsigned char* __restrict__ W2F,
                                          const unsigned char* __restrict__ W2GF,
                                          int g, int w, int l) {
    const unsigned char* a0 = W1F + (s_*4 + w)*2048 + l*16;
    const unsigned char* a1 = a0 + 1024;
    const unsigned char* b0 = W2F + (s_*4 + w)*2048 + l*16;
    const unsigned char* b1 = b0 + 1024;
    const unsigned char* c0 = W2GF + (((g*16 + s_)*4 + w) << 9) + l*8;
    asm volatile("global_load_dwordx4 %0, %1, off" : "=&v"(r.w0) : "v"(a0));
    asm volatile("global_load_dwordx4 %0, %1, off" : "=&v"(r.w1) : "v"(a1));
    asm volatile("global_load_dwordx4 %0, %1, off" : "=&v"(r.q0) : "v"(b0));
    asm volatile("global_load_dwordx4 %0, %1, off" : "=&v"(r.q1) : "v"(b1));
    asm volatile("global_load_dwordx2 %0, %1, off" : "=&v"(r.qg) : "v"(c0));
}
#define WAIT5() do { asm volatile("s_waitcnt vmcnt(5)" ::: "memory"); \
                     __builtin_amdgcn_sched_barrier(0); } while (0)
#define DRAIN() do { asm volatile("s_waitcnt vmcnt(0)" ::: "memory"); \
                     __builtin_amdgcn_sched_barrier(0); } while (0)

union U4 { uint4 q; long long l2[2]; };
union U2 { uint2 u; long long ll; };

// slab body with in-register bpermute h exchange (R22/R24/R25, verified best)
__device__ __forceinline__ void slab_body(const WR& r,
                                          const U2 (&xf)[4][2], f32x4_t (&acc2)[4][5],
                                          int idx0, int idx1, bool lo) {
    U4 w0, w1, q0, q1; w0.q = r.w0; w1.q = r.w1; q0.q = r.q0; q1.q = r.q1;
    U2 qg; qg.u = r.qg;
    #pragma unroll
    for (int mt = 0; mt < 4; ++mt) {
        f32x4_t h0 = {0.f, 0.f, 0.f, 0.f}, h1 = {0.f, 0.f, 0.f, 0.f};
        h0 = MFMA8(w0.l2[0], xf[mt][0].ll, h0);
        h0 = MFMA8(w0.l2[1], xf[mt][1].ll, h0);
        h1 = MFMA8(w1.l2[0], xf[mt][0].ll, h1);
        h1 = MFMA8(w1.l2[1], xf[mt][1].ll, h1);
        int h0w = pk4(fmaxf(h0[0],0.f), fmaxf(h0[1],0.f), fmaxf(h0[2],0.f), fmaxf(h0[3],0.f));
        int h1w = pk4(fmaxf(h1[0],0.f), fmaxf(h1[1],0.f), fmaxf(h1[2],0.f), fmaxf(h1[3],0.f));
        int p00 = __builtin_amdgcn_ds_bpermute(idx0, h0w);
        int p01 = __builtin_amdgcn_ds_bpermute(idx1, h0w);
        int p10 = __builtin_amdgcn_ds_bpermute(idx0, h1w);
        int p11 = __builtin_amdgcn_ds_bpermute(idx1, h1w);
        U2 a2;
        a2.u.x = lo ? (unsigned int)p00 : (unsigned int)p10;
        a2.u.y = lo ? (unsigned int)p01 : (unsigned int)p11;
        acc2[mt][0] = MFMA8(q0.l2[0], a2.ll, acc2[mt][0]);
        acc2[mt][1] = MFMA8(q0.l2[1], a2.ll, acc2[mt][1]);
        acc2[mt][2] = MFMA8(q1.l2[0], a2.ll, acc2[mt][2]);
        acc2[mt][3] = MFMA8(q1.l2[1], a2.ll, acc2[mt][3]);
        acc2[mt][4] = MFMA8(qg.ll,    a2.ll, acc2[mt][4]);
    }
}

// ---------------- fused + in-kernel finalize (ticket; no threadfence) ------
__global__ __launch_bounds__(256, 2) void k_fused(const float* __restrict__ x,
                                                  const unsigned char* __restrict__ W1F,
                                                  const unsigned char* __restrict__ W2F,
                                                  const unsigned char* __restrict__ W2GF,
                                                  const float* __restrict__ b2,
                                                  const float* __restrict__ y,
                                                  const float* __restrict__ centers,
                                                  const int* __restrict__ counts,
                                                  const int* __restrict__ perm,
                                                  float* __restrict__ accum,
                                                  int* __restrict__ ticket,
                                                  float* __restrict__ out) {
    __shared__ __align__(16) union {
        unsigned char xb[TS][80];   // fp8 x tile (gather phase)
        float o[TS][84];            // epilogue overlay
    } u;
    __shared__ int   rows_s[TS];
    __shared__ int   dsc[3];   // g, off, nrows

    int phys = blockIdx.x, t = threadIdx.x;
    int bid  = (phys & 7) * (MAXT / 8) + (phys >> 3);   // XCD chunk swizzle (bijective)
    int l  = t & 63;
    int w  = t >> 6;
    int lr = l & 15;
    int lg = l >> 4;

    // in-block tile descriptor: wave 0 scans counts
    if (t == 0) dsc[2] = 0;
    if (t < 64) {
        int c = counts[t];
        int ntm = (c + TS - 1) / TS;
        int sc = c, st = ntm;
        #pragma unroll
        for (int d = 1; d < 64; d <<= 1) {
            int vc = __shfl_up(sc, d);
            int vt = __shfl_up(st, d);
            if (t >= d) { sc += vc; st += vt; }
        }
        int offc  = sc - c;
        int tbase = st - ntm;
        if (bid >= tbase && bid < tbase + ntm) {
            int k = bid - tbase;
            dsc[0] = t;
            dsc[1] = offc + TS * k;
            dsc[2] = min(TS, c - TS * k);
        }
    }
    __syncthreads();
    int g = dsc[0], off = dsc[1], nrows = dsc[2];

    if (nrows == 0) {
        if (t == 0) {
            int old = atomicAdd(ticket, 1);
            if (old == MAXT - 1) {
                float ce = atomicAdd(&accum[0], 0.f);
                float ms = atomicAdd(&accum[1], 0.f);
                out[0] = ce / (float)B_N + 100.f * ms / ((float)B_N * (float)YD);
            }
        }
        return;
    }

    if (t < TS) rows_s[t] = (t < nrows) ? perm[off + t] : -1;
    __syncthreads();

    // gather x rows -> LDS fp8; col 60 = 1.0 (bias lane, e4m3 0x38), 61..79 = 0
    {
        int c4 = t & 15;
        #pragma unroll
        for (int it = 0; it < 4; ++it) {
            int r = 16 * it + (t >> 4);
            int row = rows_s[r];
            if (c4 < 15) {
                int pk = 0;
                if (row >= 0) {
                    float4 v = *reinterpret_cast<const float4*>(&x[(size_t)row * XD + 4 * c4]);
                    pk = pk4(v.x, v.y, v.z, v.w);
                }
                *reinterpret_cast<unsigned int*>(&u.xb[r][4 * c4]) = (unsigned int)pk;
            } else {
                *reinterpret_cast<unsigned int*>(&u.xb[r][60]) = (row >= 0) ? 0x00000038u : 0u;
                uint4 z = {0, 0, 0, 0};
                *reinterpret_cast<uint4*>(&u.xb[r][64]) = z;
            }
        }
    }
    __syncthreads();

    U2 xf[4][2];
    #pragma unroll
    for (int mt = 0; mt < 4; ++mt)
        #pragma unroll
        for (int ks = 0; ks < 2; ++ks)
            xf[mt][ks].u = *reinterpret_cast<const uint2*>(&u.xb[16*mt + lr][32*ks + 8*lg]);

    f32x4_t acc2[4][5];
    #pragma unroll
    for (int mt = 0; mt < 4; ++mt)
        #pragma unroll
        for (int nt = 0; nt < 5; ++nt) acc2[mt][nt] = (f32x4_t){0.f, 0.f, 0.f, 0.f};

    // bpermute indices (byte addressing: 4 * src_lane)
    int idx0 = 4 * (16 * ((2 * lg) & 3) + lr);
    int idx1 = idx0 + 64;
    bool lo  = (lg < 2);

    // depth-2 pipeline: asm loads + counted vmcnt
    WR rA, rB;
    loadw_asm(rA, 0, W1F, W2F, W2GF, g, w, l);
    #pragma unroll 1
    for (int s = 0; s < HID / 128; s += 2) {
        loadw_asm(rB, s + 1, W1F, W2F, W2GF, g, w, l);
        WAIT5();
        slab_body(rA, xf, acc2, idx0, idx1, lo);
        loadw_asm(rA, (s + 2 < 16) ? s + 2 : 0, W1F, W2F, W2GF, g, w, l);
        WAIT5();
        slab_body(rB, xf, acc2, idx0, idx1, lo);
    }
    DRAIN();           // dead in-flight tail loads complete before reg reuse
    __syncthreads();   // all xb reads done before overlaying u.o

    // epilogue: sum 4 K-partials (x 1/256 weight prescale), bias in phase 0
    const float inv = 1.f / 256.f;
    for (int wv = 0; wv < 4; ++wv) {
        if (w == wv) {
            #pragma unroll
            for (int mt = 0; mt < 4; ++mt)
                #pragma unroll
                for (int nt = 0; nt < 5; ++nt) {
                    float4 v;
                    v.x = acc2[mt][nt][0] * inv; v.y = acc2[mt][nt][1] * inv;
                    v.z = acc2[mt][nt][2] * inv; v.w = acc2[mt][nt][3] * inv;
                    float4* pp = reinterpret_cast<float4*>(&u.o[16*mt + lr][16*nt + 4*lg]);
                    if (wv == 0) {
                        float bx, by, bz, bw;
                        if (nt < 4) {
                            int c = 16*nt + 4*lg;
                            bx = b2[c]; by = b2[c+1]; bz = b2[c+2]; bw = b2[c+3];
                        } else {
                            int c = 4*lg;
                            bx = (c   < YD) ? b2[NK + g*YD + c  ] : 0.f;
                            by = (c+1 < YD) ? b2[NK + g*YD + c+1] : 0.f;
                            bz = (c+2 < YD) ? b2[NK + g*YD + c+2] : 0.f;
                            bw = (c+3 < YD) ? b2[NK + g*YD + c+3] : 0.f;
                        }
                        v.x += bx; v.y += by; v.z += bz; v.w += bw;
                        *pp = v;
                    } else {
                        float4 cur = *pp;
                        cur.x += v.x; cur.y += v.y; cur.z += v.z; cur.w += v.w;
                        *pp = cur;
                    }
                }
        }
        __syncthreads();
    }

    // per-row loss; rows 0..63 == wave 0 -> shuffle-reduce, one atomic pair
    if (t < TS) {
        float ce_v = 0.f, mse_v = 0.f;
        if (t < nrows) {
            float m = -1e30f;
            for (int c = 0; c < NK; ++c) m = fmaxf(m, u.o[t][c]);
            float s2 = 0.f;
            for (int c = 0; c < NK; ++c) s2 += expf(u.o[t][c] - m);
            float lse = m + logf(s2);
            ce_v = lse - u.o[t][g];
            int row = rows_s[t];
            #pragma unroll
            for (int j = 0; j < YD; ++j) {
                float tr = y[row * YD + j] - centers[g * YD + j];
                float d  = tr - u.o[t][NK + j];
                mse_v += d * d;
            }
        }
        #pragma unroll
        for (int d = 32; d > 0; d >>= 1) {
            ce_v  += __shfl_down(ce_v, d);
            mse_v += __shfl_down(mse_v, d);
        }
        if (t == 0) {
            atomicAdd(&accum[0], ce_v);
            atomicAdd(&accum[1], mse_v);
            asm volatile("s_waitcnt vmcnt(0)" ::: "memory");
            int old = atomicAdd(ticket, 1);
            if (old == MAXT - 1) {
                float ce = atomicAdd(&accum[0], 0.f);
                float ms = atomicAdd(&accum[1], 0.f);
                out[0] = ce / (float)B_N + 100.f * ms / ((float)B_N * (float)YD);
            }
        }
    }
}

extern "C" void kernel_launch(void* const* d_in, const int* in_sizes, int n_in,
                              void* d_out, int out_size, void* d_ws, size_t ws_size,
                              hipStream_t stream) {
    const float* x       = (const float*)d_in[0];
    const float* y       = (const float*)d_in[1];
    const float* centers = (const float*)d_in[2];
    const float* W1      = (const float*)d_in[3];
    const float* b1      = (const float*)d_in[4];
    const float* W2      = (const float*)d_in[5];
    const float* b2      = (const float*)d_in[6];

    char* ws = (char*)d_ws;
    float* accum  = (float*)ws;                        // 2 f32 (zeroed by k_b)
    int* ticket   = (int*)(ws + 128);                  // zeroed by k_b
    int* counts   = (int*)(ws + 256);                  // written by k_b
    int* hist     = (int*)(ws + 4096);                 // 128 x 64 ints (32 KB, k_a)
    char* ws2     = ws + 4096 + 32768;
    int* labels   = (int*)ws2;                                   // 128 KB
    int* perm     = (int*)(ws2 + 131072);                        // 128 KB
    unsigned char* W1F  = (unsigned char*)(ws2 + 262144);        // 128 KB
    unsigned char* W2F  = (unsigned char*)(ws2 + 393216);        // 128 KB
    unsigned char* W2GF = (unsigned char*)(ws2 + 524288);        // 2 MB

    k_a     <<<LBLK + 384, 256, 0, stream>>>(y, centers, W1, b1, W2,
                                             labels, hist, W1F, W2F, W2GF);
    k_b     <<<B_N / 256, 256, 0, stream>>>(labels, hist, counts, perm,
                                            accum, ticket);
    k_fused <<<MAXT, 256, 0, stream>>>(x, W1F, W2F, W2GF, b2, y, centers,
                                       counts, perm, accum, ticket, (float*)d_out);
}